// Round 7
// baseline (105.649 us; speedup 1.0000x reference)
//
#include <hip/hip_runtime.h>
#include <math.h>

// NCC loss, restructured:
//   sum(cross)  = A - D/225,  A = sum I*J*cnt,  D = sum S_I*S_J
//   sum(I_var)  = B - E/225,  B = sum I*I*cnt,  E = sum S_I^2
//   sum(J_var)  = C - F/225,  C = sum J*J*cnt,  F = sum S_J^2
// where S_X = 15x15 zero-padded box sum of X, cnt(i,j) = ch(i)*cw(j),
// ch(i) = min(i,7)+min(511-i,7)+1.
//
// R7: two streaming kernels instead of one barrier-heavy monolith
// (R3/R6 were latency-bound: all pipes <25% busy, 3 barriers/block).
//  - ncc_vert: thread-per-column running vertical sum in registers
//    (subtract-old via L2-hit re-read; no reg ring -> no spills, R4 lesson),
//    no LDS/barriers in hot loop; writes V float2 to d_ws; A/B/C fused.
//  - ncc_horiz: one-barrier tile kernel over V; sliding horizontal sum;
//    D/E/F partials.
//  - ncc_finalize: separate 1-block kernel (no device fences, R5 lesson).

#define IMG_H 512
#define IMG_W 512
#define NB    16
#define BAND  16            // output rows per vert block
#define NBANDS (IMG_H / BAND)            // 32
#define NVBLK (NB * NBANDS * 2)          // 1024
#define HTW   64            // horiz tile cols
#define HTH   32            // horiz tile rows
#define HSTR  81            // float2 stride: bank (2r+2x)%32 -> 2-way, free
#define NHBLK (NB * (IMG_H / HTH) * (IMG_W / HTW))   // 2048

__device__ __forceinline__ float winw(int i) {
    int a = i < 7 ? i : 7;
    int b = (511 - i) < 7 ? (511 - i) : 7;
    return (float)(a + b + 1);
}

// ---------------- vertical pass + A/B/C ----------------
__global__ __launch_bounds__(256) void ncc_vert(const float* __restrict__ I,
                                                const float* __restrict__ J,
                                                float2* __restrict__ V,
                                                float* __restrict__ P1) {
    __shared__ float redf[4 * 3];
    const int tid = threadIdx.x;
    const int c = blockIdx.x * 256 + tid;          // column, coalesced
    const int O0 = blockIdx.y * BAND;              // first output row
    const int bz = blockIdx.z;
    const float* Ib = I + (size_t)bz * IMG_H * IMG_W;
    const float* Jb = J + (size_t)bz * IMG_H * IMG_W;
    float2* Vb = V + (size_t)bz * IMG_H * IMG_W;

    const float wc = winw(c);
    float sI = 0.f, sJ = 0.f;
    float a0 = 0.f, a1 = 0.f, a2 = 0.f;

    // init: sum over rows O0-8 .. O0+6 (valid subset), so that the first
    // update (+x(O0+7) - x(O0-8)) yields the window O0-7..O0+7.
    int rstart = O0 - 8; if (rstart < 0) rstart = 0;
    for (int r = rstart; r < O0 + 7; ++r) {
        float iv = Ib[r * IMG_W + c];
        float jv = Jb[r * IMG_W + c];
        sI += iv; sJ += jv;
        if (O0 == 0) {                 // band 0 owns raw rows 0..6 here
            float w = winw(r) * wc;
            a0 += iv * jv * w;
            a1 += iv * iv * w;
            a2 += jv * jv * w;
        }
    }

    // stream: each iteration emits V(o); fresh row rT=o+7 is owned for A/B/C
    // (bands own raw rows O0+7..O0+22 -> exact cover of 7..511).
    #pragma unroll 4
    for (int o = O0; o < O0 + BAND; ++o) {
        int rT = o + 7, rB = o - 8;
        float ivT = 0.f, jvT = 0.f;
        if (rT < IMG_H) {
            ivT = Ib[rT * IMG_W + c];
            jvT = Jb[rT * IMG_W + c];
            float w = winw(rT) * wc;
            a0 += ivT * jvT * w;
            a1 += ivT * ivT * w;
            a2 += jvT * jvT * w;
        }
        float ivB = 0.f, jvB = 0.f;
        if (rB >= 0) {
            ivB = Ib[rB * IMG_W + c];   // L2-hit re-read
            jvB = Jb[rB * IMG_W + c];
        }
        sI += ivT - ivB;
        sJ += jvT - jvB;
        Vb[o * IMG_W + c] = make_float2(sI, sJ);
    }

    // block reduction of a0..a2
    float vals[3] = {a0, a1, a2};
    #pragma unroll
    for (int k = 0; k < 3; ++k) {
        float v = vals[k];
        #pragma unroll
        for (int off = 32; off > 0; off >>= 1) v += __shfl_down(v, off, 64);
        vals[k] = v;
    }
    int wave = tid >> 6, lane = tid & 63;
    if (lane == 0) {
        #pragma unroll
        for (int k = 0; k < 3; ++k) redf[wave * 3 + k] = vals[k];
    }
    __syncthreads();
    if (tid == 0) {
        int bid = (bz * NBANDS + blockIdx.y) * 2 + blockIdx.x;
        #pragma unroll
        for (int k = 0; k < 3; ++k)
            P1[bid * 3 + k] = redf[k] + redf[3 + k] + redf[6 + k] + redf[9 + k];
    }
}

// ---------------- horizontal pass + D/E/F ----------------
__global__ __launch_bounds__(256) void ncc_horiz(const float2* __restrict__ V,
                                                 float* __restrict__ P2) {
    __shared__ float2 buf[HTH * HSTR];   // 20.7 KB
    __shared__ float redf[4 * 3];
    const int tid = threadIdx.x;
    const int tx = blockIdx.x, ty = blockIdx.y, bz = blockIdx.z;
    const int C0 = tx * HTW - 8;         // stored V-col of buf col 0 (even)
    const int Rt = ty * HTH;
    const float2* Vb = V + (size_t)bz * IMG_H * IMG_W;

    // load 32 rows x 40 float4 (80 float2 cols C0..C0+79), zero-pad OOB
    for (int k = tid; k < HTH * 40; k += 256) {
        int r = k / 40, f = k - (k / 40) * 40;
        int vc = C0 + 2 * f;             // first of two V-cols (even)
        float4 x = make_float4(0.f, 0.f, 0.f, 0.f);
        if ((unsigned)vc < (unsigned)(IMG_W - 1)) {   // vc>=0 && vc+1<=511
            x = *reinterpret_cast<const float4*>(&Vb[(Rt + r) * IMG_W + vc]);
        }
        buf[r * HSTR + 2 * f]     = make_float2(x.x, x.y);
        buf[r * HSTR + 2 * f + 1] = make_float2(x.z, x.w);
    }
    __syncthreads();

    // sliding horizontal 15-sum; thread = (row r, 8-col run ch)
    float d0 = 0.f, e0 = 0.f, f0 = 0.f;
    {
        int r = tid & 31;
        int ch = tid >> 5;
        int base = r * HSTR + ch * 8 + 1;    // V col (C + ch*8) - 7
        float2 v[22];
        #pragma unroll
        for (int i = 0; i < 22; ++i) v[i] = buf[base + i];
        float sI = 0.f, sJ = 0.f;
        #pragma unroll
        for (int i = 0; i < 15; ++i) { sI += v[i].x; sJ += v[i].y; }
        d0 += sI * sJ; e0 += sI * sI; f0 += sJ * sJ;
        #pragma unroll
        for (int i = 1; i < 8; ++i) {
            sI += v[i + 14].x - v[i - 1].x;
            sJ += v[i + 14].y - v[i - 1].y;
            d0 += sI * sJ; e0 += sI * sI; f0 += sJ * sJ;
        }
    }

    float vals[3] = {d0, e0, f0};
    #pragma unroll
    for (int k = 0; k < 3; ++k) {
        float v = vals[k];
        #pragma unroll
        for (int off = 32; off > 0; off >>= 1) v += __shfl_down(v, off, 64);
        vals[k] = v;
    }
    int wave = tid >> 6, lane = tid & 63;
    if (lane == 0) {
        #pragma unroll
        for (int k = 0; k < 3; ++k) redf[wave * 3 + k] = vals[k];
    }
    __syncthreads();
    if (tid == 0) {
        int bid = ((bz * (IMG_H / HTH)) + ty) * (IMG_W / HTW) + tx;
        #pragma unroll
        for (int k = 0; k < 3; ++k)
            P2[bid * 3 + k] = redf[k] + redf[3 + k] + redf[6 + k] + redf[9 + k];
    }
}

// ---------------- finalize ----------------
__global__ __launch_bounds__(256) void ncc_finalize(const float* __restrict__ P1,
                                                    const float* __restrict__ P2,
                                                    float* __restrict__ out) {
    __shared__ double red[4 * 6];
    int tid = threadIdx.x;
    double acc[6] = {0, 0, 0, 0, 0, 0};
    for (int b = tid; b < NVBLK; b += 256) {
        #pragma unroll
        for (int k = 0; k < 3; ++k) acc[k] += (double)P1[b * 3 + k];
    }
    for (int b = tid; b < NHBLK; b += 256) {
        #pragma unroll
        for (int k = 0; k < 3; ++k) acc[3 + k] += (double)P2[b * 3 + k];
    }
    #pragma unroll
    for (int k = 0; k < 6; ++k) {
        double v = acc[k];
        #pragma unroll
        for (int off = 32; off > 0; off >>= 1) v += __shfl_down(v, off, 64);
        acc[k] = v;
    }
    int wave = tid >> 6, lane = tid & 63;
    if (lane == 0) {
        #pragma unroll
        for (int k = 0; k < 6; ++k) red[wave * 6 + k] = acc[k];
    }
    __syncthreads();
    if (tid == 0) {
        double s[6];
        #pragma unroll
        for (int k = 0; k < 6; ++k) s[k] = red[k] + red[6 + k] + red[12 + k] + red[18 + k];
        double A = s[0], Bv = s[1], Cv = s[2], D = s[3], E = s[4], F = s[5];
        double num = A - D / 225.0;
        double varI = Bv - E / 225.0;
        double varJ = Cv - F / 225.0;
        double cc = num / sqrt(varI * varJ);
        out[0] = (float)(-cc);
    }
}

extern "C" void kernel_launch(void* const* d_in, const int* in_sizes, int n_in,
                              void* d_out, int out_size, void* d_ws, size_t ws_size,
                              hipStream_t stream) {
    const float* I = (const float*)d_in[0];
    const float* J = (const float*)d_in[1];
    float2* V = (float2*)d_ws;                                   // 33.5 MB
    float* P1 = (float*)((char*)d_ws + (size_t)NB * IMG_H * IMG_W * sizeof(float2));
    float* P2 = P1 + NVBLK * 3;

    dim3 gv(2, NBANDS, NB);              // 1024 blocks
    ncc_vert<<<gv, 256, 0, stream>>>(I, J, V, P1);
    dim3 gh(IMG_W / HTW, IMG_H / HTH, NB);   // 2048 blocks
    ncc_horiz<<<gh, 256, 0, stream>>>(V, P2);
    ncc_finalize<<<1, 256, 0, stream>>>(P1, P2, (float*)d_out);
}

// Round 8
// 93.349 us; speedup vs baseline: 1.1318x; 1.1318x over previous
//
#include <hip/hip_runtime.h>
#include <math.h>

// NCC loss, restructured:
//   sum(cross)  = A - D/225,  A = sum I*J*cnt,  D = sum S_I*S_J
//   sum(I_var)  = B - E/225,  B = sum I*I*cnt,  E = sum S_I^2
//   sum(J_var)  = C - F/225,  C = sum J*J*cnt,  F = sum S_J^2
// where S_X = 15x15 zero-padded box sum of X, cnt(i,j) = ch(i)*cw(j),
// ch(i) = min(i,7)+min(511-i,7)+1.
//
// R8: single main kernel, NO raw-pixel LDS staging. Vertical 15-tap sums
// computed in registers straight from global (coalesced, L2/L3-warm),
// written to LDS as float2 V; one barrier; horizontal sliding (R7's proven
// pattern) for D/E/F. A/B/C fused into the load with exact ownership.
// LDS 50->20 KB (3->~6 blocks/CU), barriers 3->2, LDS ops ~halved.
// Register arrays are 25/image (static-indexed, full unroll) - below R4's
// spill regime; __launch_bounds__(256,4) caps VGPR at 128.

#define IMG_H 512
#define IMG_W 512
#define NB    16
#define TW    64
#define TH    32
#define SPAN_C 78                        // TW + 14 columns of V
#define S2    79                         // float2 row stride (odd granule)
#define NTX   8                          // 512/64
#define NTY   16                         // 512/32
#define NBLK  (NB * NTX * NTY)           // 2048

__device__ __forceinline__ float winw(int i) {
    int a = i < 7 ? i : 7;
    int b = (511 - i) < 7 ? (511 - i) : 7;
    return (float)(a + b + 1);
}

__global__ __launch_bounds__(256, 4) void ncc_main(const float* __restrict__ I,
                                                   const float* __restrict__ J,
                                                   float* __restrict__ partials) {
    __shared__ float2 V[TH * S2];        // 20.2 KB: (S_I_vert, S_J_vert)
    __shared__ float redf[4 * 6];

    const int tid = threadIdx.x;
    const int tx = blockIdx.x, ty = blockIdx.y, bz = blockIdx.z;
    const int R0 = ty * TH;              // first output row of tile
    const int C0 = tx * TW;              // first output col of tile
    const float* Ib = I + (size_t)bz * IMG_H * IMG_W;
    const float* Jb = J + (size_t)bz * IMG_H * IMG_W;

    float a0 = 0.f, a1 = 0.f, a2 = 0.f;

    // ---- stage V: vertical sums in registers, direct from global ----
    // thread = (column cl of 78, band of rows). Bands: rows 0-10, 11-21,
    // 22-31. Band loads raw rel rows r0-7 .. r0+nr+6 (<=25 per image).
    {
        int band = tid / SPAN_C;         // 0..2 active, 3 idle (tid>=234)
        int cl = tid - band * SPAN_C;    // 0..77
        if (band < 3) {
            const int r0     = (band == 0) ? 0 : (band == 1) ? 11 : 22;
            const int nr     = (band == 2) ? 10 : 11;
            const int nraw   = nr + 14;                  // 25 or 24
            const int own_lo = (band == 0) ? 0 : (band == 1) ? 18 : 29;
            const int own_hi = (band == 0) ? 17 : (band == 1) ? 28 : 31;
            const int gc = C0 - 7 + cl;                  // global column
            const bool colok = (unsigned)gc < (unsigned)IMG_W;
            const bool own_c = (cl >= 7 && cl <= 70);    // interior col
            const float wc = colok ? winw(gc) : 0.f;
            const float* Ip = Ib + gc;
            const float* Jp = Jb + gc;

            float rI[25], rJ[25];
            #pragma unroll
            for (int t = 0; t < 25; ++t) {
                int rel = r0 - 7 + t;
                int gr = R0 + rel;
                float iv = 0.f, jv = 0.f;
                if (t < nraw && colok && (unsigned)gr < (unsigned)IMG_H) {
                    iv = Ip[gr * IMG_W];
                    jv = Jp[gr * IMG_W];
                }
                rI[t] = iv; rJ[t] = jv;
                // A/B/C: each block owns raw rows R0..R0+31 x cols C0..C0+63;
                // bands partition rel rows 0..31 as 0-17 / 18-28 / 29-31.
                if (t < nraw && own_c && rel >= own_lo && rel <= own_hi) {
                    float w = winw(gr) * wc;
                    a0 += iv * jv * w;
                    a1 += iv * iv * w;
                    a2 += jv * jv * w;
                }
            }
            // vertical 15-tap sliding sum over the register window
            float sI = 0.f, sJ = 0.f;
            #pragma unroll
            for (int t = 0; t < 15; ++t) { sI += rI[t]; sJ += rJ[t]; }
            V[r0 * S2 + cl] = make_float2(sI, sJ);
            #pragma unroll
            for (int k = 1; k < 11; ++k) {
                if (k < nr) {
                    sI += rI[14 + k] - rI[k - 1];
                    sJ += rJ[14 + k] - rJ[k - 1];
                    V[(r0 + k) * S2 + cl] = make_float2(sI, sJ);
                }
            }
        }
    }
    __syncthreads();

    // ---- stage H: horizontal 15-tap sliding over V (proven R3/R7 form) ----
    float a3 = 0.f, a4 = 0.f, a5 = 0.f;
    {
        int r = tid & 31;                // output row in tile
        int ch = tid >> 5;               // 0..7 -> 8 output cols each
        int base = r * S2 + ch * 8;      // V col (C0+ch*8) - 7
        float2 v[22];
        #pragma unroll
        for (int i = 0; i < 22; ++i) v[i] = V[base + i];
        float sI = 0.f, sJ = 0.f;
        #pragma unroll
        for (int i = 0; i < 15; ++i) { sI += v[i].x; sJ += v[i].y; }
        a3 += sI * sJ; a4 += sI * sI; a5 += sJ * sJ;
        #pragma unroll
        for (int i = 1; i < 8; ++i) {
            sI += v[i + 14].x - v[i - 1].x;
            sJ += v[i + 14].y - v[i - 1].y;
            a3 += sI * sJ; a4 += sI * sI; a5 += sJ * sJ;
        }
    }

    // ---- block reduction: wave shuffle then LDS across the 4 waves ----
    float vals[6] = {a0, a1, a2, a3, a4, a5};
    #pragma unroll
    for (int k = 0; k < 6; ++k) {
        float v = vals[k];
        #pragma unroll
        for (int off = 32; off > 0; off >>= 1) v += __shfl_down(v, off, 64);
        vals[k] = v;
    }
    int wave = tid >> 6, lane = tid & 63;
    if (lane == 0) {
        #pragma unroll
        for (int k = 0; k < 6; ++k) redf[wave * 6 + k] = vals[k];
    }
    __syncthreads();
    if (tid == 0) {
        int bidx = (bz * NTY + ty) * NTX + tx;
        #pragma unroll
        for (int k = 0; k < 6; ++k) {
            partials[bidx * 6 + k] = redf[k] + redf[6 + k] + redf[12 + k] + redf[18 + k];
        }
    }
}

__global__ __launch_bounds__(256) void ncc_finalize(const float* __restrict__ partials,
                                                    float* __restrict__ out) {
    __shared__ double red[4 * 6];
    int tid = threadIdx.x;
    double acc[6] = {0, 0, 0, 0, 0, 0};
    for (int b = tid; b < NBLK; b += 256) {
        #pragma unroll
        for (int k = 0; k < 6; ++k) acc[k] += (double)partials[b * 6 + k];
    }
    #pragma unroll
    for (int k = 0; k < 6; ++k) {
        double v = acc[k];
        #pragma unroll
        for (int off = 32; off > 0; off >>= 1) v += __shfl_down(v, off, 64);
        acc[k] = v;
    }
    int wave = tid >> 6, lane = tid & 63;
    if (lane == 0) {
        #pragma unroll
        for (int k = 0; k < 6; ++k) red[wave * 6 + k] = acc[k];
    }
    __syncthreads();
    if (tid == 0) {
        double s[6];
        #pragma unroll
        for (int k = 0; k < 6; ++k) s[k] = red[k] + red[6 + k] + red[12 + k] + red[18 + k];
        double A = s[0], Bv = s[1], Cv = s[2], D = s[3], E = s[4], F = s[5];
        double num = A - D / 225.0;
        double varI = Bv - E / 225.0;
        double varJ = Cv - F / 225.0;
        double cc = num / sqrt(varI * varJ);
        out[0] = (float)(-cc);
    }
}

extern "C" void kernel_launch(void* const* d_in, const int* in_sizes, int n_in,
                              void* d_out, int out_size, void* d_ws, size_t ws_size,
                              hipStream_t stream) {
    const float* I = (const float*)d_in[0];
    const float* J = (const float*)d_in[1];
    float* partials = (float*)d_ws;      // NBLK*6 floats = 48 KB

    dim3 grid(NTX, NTY, NB);
    ncc_main<<<grid, 256, 0, stream>>>(I, J, partials);
    ncc_finalize<<<1, 256, 0, stream>>>(partials, (float*)d_out);
}